// Round 12
// baseline (333.993 us; speedup 1.0000x reference)
//
#include <hip/hip_runtime.h>
#include <math.h>

// SimpPointNet round 12: e3 moved to full-K slabs (SB32=4, SPC=1, MINW=1) — r10->r11
// showed bigger slabs + deeper prefetch beat occupancy (60->42us at 4->2 blocks/CU);
// this pushes to prefetch-a-full-chunk-ahead (64 MFMA/wave of cover per barrier).
// k_e1fin folded into k_e1 (each block reduces the 2.3KB moment partials locally).
// Everything else identical to round 11. M = B*N = 65536, m = b*2048 + n.

#define M_TOTAL 65536
#define BN_EPS 1e-5f
#define W_THRESH 1e-4f

typedef __attribute__((ext_vector_type(8))) _Float16 f16x8;
typedef __attribute__((ext_vector_type(2))) _Float16 half2v;
typedef __attribute__((ext_vector_type(4))) float f32x4;

__device__ __forceinline__ unsigned short f2h(float f) {
    _Float16 h = (_Float16)f;
    return __builtin_bit_cast(unsigned short, h);
}
__device__ __forceinline__ float h2f(unsigned short u) {
    return (float)__builtin_bit_cast(_Float16, u);
}

// async global->LDS, 16B per lane; per-lane source vaddr, LDS dest = uniform base + lane*16
__device__ __forceinline__ void cp16(unsigned short* lds, const unsigned short* g) {
    __builtin_amdgcn_global_load_lds(
        (const __attribute__((address_space(1))) unsigned int*)(const void*)g,
        (__attribute__((address_space(3))) unsigned int*)(void*)lds,
        16, 0, 0);
}

// ---- convert all 5 GEMM weight matrices to MFMA-fragment-ordered fp16 ----
// Tile (ob, kb32, ot): 64 lanes x 8 halves; lane l -> W[ob*128+ot*16+(l&15)][kb32*32+(l>>4)*8..+8]
// Flat: Wf[ ((ob*KB32 + kb32)*8 + ot)*512 + l*8 ]
__global__ void k_wprep(const float* __restrict__ e_w2, const float* __restrict__ e_w3,
                        const float* __restrict__ hw1, const float* __restrict__ h_w2,
                        const float* __restrict__ h_w3,
                        unsigned short* We2, unsigned short* We3, unsigned short* Wh1,
                        unsigned short* Wh2, unsigned short* Wh3) {
    int t = blockIdx.x;
    const float* W; int ldw, KB; unsigned short* D; int rel;
    if (t < 16)       { W = e_w2;       ldw = 64;   KB = 2;  D = We2; rel = t; }
    else if (t < 272) { W = e_w3;       ldw = 128;  KB = 4;  D = We3; rel = t - 16; }
    else if (t < 336) { W = hw1 + 1024; ldw = 1088; KB = 2;  D = Wh1; rel = t - 272; }
    else if (t < 592) { W = h_w2;       ldw = 512;  KB = 16; D = Wh2; rel = t - 336; }
    else              { W = h_w3;       ldw = 256;  KB = 8;  D = Wh3; rel = t - 592; }
    int ot = rel & 7, kb = (rel >> 3) % KB, ob = rel / (8 * KB);
    int l = threadIdx.x;
    int o = ob * 128 + ot * 16 + (l & 15);
    int k = kb * 32 + (l >> 4) * 8;
    const float* src = W + (size_t)o * ldw + k;
    float4 wa = *(const float4*)src;
    float4 wb = *(const float4*)(src + 4);
    uint4 pk;
    pk.x = (unsigned)f2h(wa.x) | ((unsigned)f2h(wa.y) << 16);
    pk.y = (unsigned)f2h(wa.z) | ((unsigned)f2h(wa.w) << 16);
    pk.z = (unsigned)f2h(wb.x) | ((unsigned)f2h(wb.y) << 16);
    pk.w = (unsigned)f2h(wb.z) | ((unsigned)f2h(wb.w) << 16);
    *(uint4*)(D + (size_t)rel * 512 + l * 8) = pk;
}

// ---- point second moments -> per-block partials momP[64][9] ----
__global__ void k_moments(const float* __restrict__ pts, float* __restrict__ momP) {
    float s[9] = {0,0,0,0,0,0,0,0,0};
    for (int m = blockIdx.x * 256 + threadIdx.x; m < M_TOTAL; m += gridDim.x * 256) {
        int b = m >> 11, n = m & 2047;
        const float* p = pts + b * 6144 + n;
        float x = p[0], y = p[2048], z = p[4096];
        s[0] += x; s[1] += y; s[2] += z;
        s[3] += x * x; s[4] += y * y; s[5] += z * z;
        s[6] += x * y; s[7] += x * z; s[8] += y * z;
    }
    for (int off = 32; off; off >>= 1)
#pragma unroll
        for (int i = 0; i < 9; i++) s[i] += __shfl_down(s[i], off);
    __shared__ float red[4][9];
    int lane = threadIdx.x & 63, wv = threadIdx.x >> 6;
    if (lane == 0)
        for (int i = 0; i < 9; i++) red[wv][i] = s[i];
    __syncthreads();
    if (threadIdx.x < 9)
        momP[blockIdx.x * 9 + threadIdx.x] =
            red[0][threadIdx.x] + red[1][threadIdx.x] + red[2][threadIdx.x] + red[3][threadIdx.x];
}

// ---- e1: 3 -> 64, POST-BN+ReLU fp16 output [M][64]; BN params computed in-block
// from moment partials (folds the old k_e1fin launch) ----
__global__ void k_e1(const float* __restrict__ pts, const float* __restrict__ w,
                     const float* __restrict__ bias, const float* __restrict__ g1,
                     const float* __restrict__ be1, const float* __restrict__ momP,
                     unsigned short* __restrict__ Y) {
    __shared__ float wl[192], bl[64], al[64], sl[64], m9[9];
    int tid = threadIdx.x;
    if (tid < 192) wl[tid] = w[tid];
    if (tid < 64) bl[tid] = bias[tid];
    if (tid >= 192 && tid < 201) {
        int i = tid - 192;
        float t = 0.f;
        for (int k = 0; k < 64; k++) t += momP[k * 9 + i];
        m9[i] = t;
    }
    __syncthreads();
    if (tid < 64) {
        int o = tid;
        float w0 = wl[o * 3], w1 = wl[o * 3 + 1], w2 = wl[o * 3 + 2], b = bl[o];
        float wS1 = w0 * m9[0] + w1 * m9[1] + w2 * m9[2];
        float sum = wS1 + 65536.f * b;
        float sumsq = w0 * w0 * m9[3] + w1 * w1 * m9[4] + w2 * w2 * m9[5]
                    + 2.f * (w0 * w1 * m9[6] + w0 * w2 * m9[7] + w1 * w2 * m9[8])
                    + 2.f * b * wS1 + 65536.f * b * b;
        float mean = sum * (1.f / 65536.f);
        float var = sumsq * (1.f / 65536.f) - mean * mean;
        float ac = g1[o] * rsqrtf(var + BN_EPS);
        al[o] = ac;
        sl[o] = be1[o] - mean * ac;
    }
    __syncthreads();
    int m = blockIdx.x * 256 + tid;
    int b = m >> 11, n = m & 2047;
    const float* p = pts + b * 6144 + n;
    float px = p[0], py = p[2048], pz = p[4096];
    unsigned short* yr = Y + (size_t)m * 64;
#pragma unroll
    for (int o8 = 0; o8 < 64; o8 += 8) {
        unsigned pkw[4];
#pragma unroll
        for (int t = 0; t < 4; t++) {
            int o = o8 + t * 2;
            float v0 = fmaf(wl[o * 3 + 0], px, fmaf(wl[o * 3 + 1], py, fmaf(wl[o * 3 + 2], pz, bl[o])));
            float v1 = fmaf(wl[o * 3 + 3], px, fmaf(wl[o * 3 + 4], py, fmaf(wl[o * 3 + 5], pz, bl[o + 1])));
            float y0 = fmaxf(fmaf(al[o], v0, sl[o]), 0.f);
            float y1 = fmaxf(fmaf(al[o + 1], v1, sl[o + 1]), 0.f);
            pkw[t] = (unsigned)f2h(y0) | ((unsigned)f2h(y1) << 16);
        }
        uint4 pk; pk.x = pkw[0]; pk.y = pkw[1]; pk.z = pkw[2]; pk.w = pkw[3];
        *(uint4*)(yr + o8) = pk;
    }
}

// ---- reduce S slot partials -> BN (a,s) ----
__global__ void k_redfin(const float* __restrict__ Ps, const float* __restrict__ Pq,
                         int C, int S,
                         const float* __restrict__ g, const float* __restrict__ be,
                         float* __restrict__ a, float* __restrict__ s) {
    int cl = threadIdx.x & 63, strip = threadIdx.x >> 6;  // 16 strips x 64 ch
    int c = blockIdx.x * 64 + cl;
    float sm = 0.f, q = 0.f;
    for (int k = strip; k < S; k += 16) {
        sm += Ps[(size_t)k * C + c];
        q += Pq[(size_t)k * C + c];
    }
    __shared__ float rs[16][64], rq[16][64];
    rs[strip][cl] = sm; rq[strip][cl] = q;
    __syncthreads();
    if (threadIdx.x < 64) {
        float S2 = 0.f, Q = 0.f;
#pragma unroll
        for (int t = 0; t < 16; t++) { S2 += rs[t][cl]; Q += rq[t][cl]; }
        float mean = S2 * (1.f / M_TOTAL);
        float var = Q * (1.f / M_TOTAL) - mean * mean;
        float ac = g[c] * rsqrtf(var + BN_EPS);
        a[c] = ac;
        s[c] = be[c] - mean * ac;
    }
}

// ---- unified slab-pipelined MFMA GEMM ----
// Block: 128-o panel x (CHUNKS x 128)-m. 4 waves (wo=wave>>1, wm=wave&1), wave = 4x4
// tiles of 16x16x32 f16. B staged in SB32*32-k slabs, dbuf by step parity (LDS address
// offset). A: resident (ARES, staged once) or slab-dbuf. Prefetch for step+1 issued
// before step's compute. Store: 32-row x 4-phase transpose on the retired B buffer.
// MINW: __launch_bounds__ min-waves/EU (1 for the 96KB-LDS e3 config).
template <bool STORE, bool MINMAX, bool BIAS_BO, bool BNB, int KB32, int SB32, int CHUNKS, bool ARES, int MINW>
__launch_bounds__(256, MINW)
__global__ void k_mg(const unsigned short* __restrict__ Wf, int O,
                     const unsigned short* __restrict__ X,
                     const float* __restrict__ a_in, const float* __restrict__ s_in,
                     const float* __restrict__ bias,
                     unsigned short* __restrict__ Y,
                     float* __restrict__ Psum, float* __restrict__ Psq,
                     float* __restrict__ Pmax, float* __restrict__ Pmn) {
    constexpr int K = KB32 * 32;
    constexpr int SPC = KB32 / SB32;      // steps per chunk
    constexpr int NSTEPS = CHUNKS * SPC;
    constexpr int BT = SB32 * 8;          // tiles per slab
    constexpr int BSZ = BT * 512;         // halves per buffer
    constexpr int ASZ = ARES ? KB32 * 8 * 512 : 2 * BSZ;
    __shared__ __align__(16) unsigned short sA[ASZ];
    __shared__ __align__(16) unsigned short sB[2][BSZ];
    __shared__ _Float16 sah[BNB ? K : 2], ssb[BNB ? K : 2];
    int tid = threadIdx.x, lane = tid & 63, wave = tid >> 6;
    int wo = wave >> 1, wm = wave & 1;
    int q = lane >> 4, lc = lane & 15;
    int m0 = blockIdx.x * (128 * CHUNKS), o0 = blockIdx.y * 128;
    int bidx = m0 >> 11;

    if constexpr (BNB)
        for (int c = tid; c < K; c += 256) {
            sah[c] = (_Float16)a_in[c];
            ssb[c] = (_Float16)s_in[c];
        }

    const unsigned short* aSrc = Wf + (size_t)blockIdx.y * KB32 * 8 * 512 + lane * 8;

    auto stageB = [&](int cc, int ssl, int buf) {
#pragma unroll
        for (int t = wave; t < BT; t += 4) {
            int kb = t >> 3, mt = t & 7;
            const unsigned short* src = X
                + (size_t)(m0 + cc * 128 + mt * 16 + (lane & 15)) * K
                + (ssl * SB32 + kb) * 32 + ((lane >> 4) * 8);
            cp16(&sB[buf][t * 512], src);
        }
    };
    auto stageA = [&](int ssl, int buf) {
#pragma unroll
        for (int t = wave; t < BT; t += 4)
            cp16(&sA[buf * BSZ + t * 512], aSrc + (size_t)(ssl * SB32 * 8 + t) * 512);
    };

    // initial staging
    if constexpr (ARES) {
#pragma unroll
        for (int t = wave; t < KB32 * 8; t += 4)
            cp16(&sA[t * 512], aSrc + (size_t)t * 512);
    } else {
        stageA(0, 0);
    }
    stageB(0, 0, 0);

    f32x4 acc[4][4];
#pragma unroll
    for (int i = 0; i < 4; i++)
#pragma unroll
        for (int j = 0; j < 4; j++) acc[i][j] = (f32x4){0.f, 0.f, 0.f, 0.f};
    float sAcc[4][4] = {}, qAcc[4][4] = {};
    float mxA[4][4], mnA[4][4];
    if constexpr (MINMAX) {
#pragma unroll
        for (int i = 0; i < 4; i++)
#pragma unroll
            for (int r = 0; r < 4; r++) { mxA[i][r] = -3.4e38f; mnA[i][r] = 3.4e38f; }
    }

    __syncthreads();  // startup drain: A(+slab0) and B slab 0 landed

    for (int c = 0; c < CHUNKS; c++) {
#pragma unroll
        for (int ss = 0; ss < SPC; ss++) {
            if (c > 0 || ss > 0) __syncthreads();  // drains staging issued one step ago
            int step = c * SPC + ss;
            if (step + 1 < NSTEPS) {               // prefetch next step
                int wrap = (ss == SPC - 1) ? 1 : 0;
                int nc = c + wrap;
                int nss = wrap ? 0 : ss + 1;
                int nbuf = (step + 1) & 1;
                stageB(nc, nss, nbuf);
                if constexpr (!ARES) stageA(nss, nbuf);
            }
            int p = step & 1;
            const unsigned short* bb = sB[p];
            const unsigned short* ab = ARES ? sA : sA + p * BSZ;
#pragma unroll
            for (int kb = 0; kb < SB32; kb++) {
                f16x8 af[4], bf[4];
                int tA = ARES ? ((ss * SB32 + kb) * 8) : (kb * 8);
#pragma unroll
                for (int i = 0; i < 4; i++)
                    af[i] = *(const f16x8*)&ab[(tA + wo * 4 + i) * 512 + lane * 8];
#pragma unroll
                for (int j = 0; j < 4; j++)
                    bf[j] = *(const f16x8*)&bb[(kb * 8 + wm * 4 + j) * 512 + lane * 8];

                if constexpr (BNB) {
                    int ka = (ss * SB32 + kb) * 32 + (lane >> 4) * 8;
                    half2v a2[4], s2[4];
#pragma unroll
                    for (int t = 0; t < 4; t++) {
                        a2[t] = *(const half2v*)&sah[ka + 2 * t];
                        s2[t] = *(const half2v*)&ssb[ka + 2 * t];
                    }
                    half2v z2 = (half2v)(_Float16)0;
#pragma unroll
                    for (int j = 0; j < 4; j++) {
                        half2v* pb = (half2v*)&bf[j];
#pragma unroll
                        for (int t = 0; t < 4; t++)
                            pb[t] = __builtin_elementwise_max(a2[t] * pb[t] + s2[t], z2);
                    }
                }
#pragma unroll
                for (int i = 0; i < 4; i++)
#pragma unroll
                    for (int j = 0; j < 4; j++)
                        acc[i][j] = __builtin_amdgcn_mfma_f32_16x16x32_f16(af[i], bf[j], acc[i][j], 0, 0, 0);
            }
        }

        // ---- chunk epilogue: fold stats; store via transpose in retired B buffer ----
#pragma unroll
        for (int i = 0; i < 4; i++)
#pragma unroll
            for (int j = 0; j < 4; j++)
#pragma unroll
                for (int r = 0; r < 4; r++) {
                    float v = acc[i][j][r];
                    sAcc[i][r] += v;
                    qAcc[i][r] = fmaf(v, v, qAcc[i][r]);
                    if constexpr (MINMAX) {
                        mxA[i][r] = fmaxf(mxA[i][r], v);
                        mnA[i][r] = fminf(mnA[i][r], v);
                    }
                }

        if constexpr (STORE) {
            int pLast = (c * SPC + SPC - 1) & 1;
            short* sT = (short*)&sB[pLast][0];  // retired buffer; prefetch targets the other
            int mbase = m0 + c * 128;
            __syncthreads();  // all waves done reading sB[pLast]
#pragma unroll
            for (int ch = 0; ch < 4; ch++) {
                if (wm == (ch >> 1)) {
                    int jlo = (ch & 1) * 2;
#pragma unroll
                    for (int i = 0; i < 4; i++) {
                        int ob = o0 + wo * 64 + i * 16 + q * 4;
                        float b0 = BIAS_BO ? bias[bidx * O + ob + 0] : bias[ob + 0];
                        float b1 = BIAS_BO ? bias[bidx * O + ob + 1] : bias[ob + 1];
                        float b2 = BIAS_BO ? bias[bidx * O + ob + 2] : bias[ob + 2];
                        float b3 = BIAS_BO ? bias[bidx * O + ob + 3] : bias[ob + 3];
#pragma unroll
                        for (int jj = 0; jj < 2; jj++) {
                            int j = jlo + jj;
                            int row = jj * 16 + lc;
                            int c0 = wo * 64 + i * 16 + q * 4;
                            uint2 pk;
                            pk.x = (unsigned)f2h(acc[i][j][0] + b0) | ((unsigned)f2h(acc[i][j][1] + b1) << 16);
                            pk.y = (unsigned)f2h(acc[i][j][2] + b2) | ((unsigned)f2h(acc[i][j][3] + b3) << 16);
                            *(uint2*)&sT[row * 136 + c0] = pk;
                        }
                    }
                }
                __syncthreads();
                {
                    int row = tid >> 4, c0 = (tid & 15) * 8;
#pragma unroll
                    for (int rr = 0; rr < 2; rr++) {
                        int r2 = row + rr * 16;
                        int m = mbase + ch * 32 + r2;
                        uint4 v = *(const uint4*)&sT[r2 * 136 + c0];
                        *(uint4*)(Y + (size_t)m * O + o0 + c0) = v;
                    }
                }
                __syncthreads();
            }
        }

        if (c + 1 < CHUNKS) {
#pragma unroll
            for (int i = 0; i < 4; i++)
#pragma unroll
                for (int j = 0; j < 4; j++) acc[i][j] = (f32x4){0.f, 0.f, 0.f, 0.f};
        }
    }

    // ---- final: 16-lane reduce, bias correction, one partial write per block ----
    int slot = blockIdx.x * 2 + wm;
    const float NM = 64.f * CHUNKS;
#pragma unroll
    for (int i = 0; i < 4; i++) {
        int ob = o0 + wo * 64 + i * 16 + q * 4;
        float s4[4], q4[4], mx[4], mn[4];
#pragma unroll
        for (int r = 0; r < 4; r++) {
            s4[r] = sAcc[i][r]; q4[r] = qAcc[i][r];
            if constexpr (MINMAX) { mx[r] = mxA[i][r]; mn[r] = mnA[i][r]; }
        }
#pragma unroll
        for (int off = 1; off < 16; off <<= 1)
#pragma unroll
            for (int r = 0; r < 4; r++) {
                s4[r] += __shfl_xor(s4[r], off);
                q4[r] += __shfl_xor(q4[r], off);
                if constexpr (MINMAX) {
                    mx[r] = fmaxf(mx[r], __shfl_xor(mx[r], off));
                    mn[r] = fminf(mn[r], __shfl_xor(mn[r], off));
                }
            }
        if (lc == 0) {
            float S4[4], Q4[4];
#pragma unroll
            for (int r = 0; r < 4; r++) {
                float bv = BIAS_BO ? bias[bidx * O + ob + r] : bias[ob + r];
                S4[r] = s4[r] + NM * bv;
                Q4[r] = q4[r] + 2.f * bv * s4[r] + NM * bv * bv;
                if constexpr (MINMAX) { mx[r] += bv; mn[r] += bv; }
            }
            *(float4*)&Psum[(size_t)slot * O + ob] = make_float4(S4[0], S4[1], S4[2], S4[3]);
            *(float4*)&Psq[(size_t)slot * O + ob] = make_float4(Q4[0], Q4[1], Q4[2], Q4[3]);
            if constexpr (MINMAX) {
                *(float4*)&Pmax[(size_t)slot * O + ob] = make_float4(mx[0], mx[1], mx[2], mx[3]);
                *(float4*)&Pmn[(size_t)slot * O + ob] = make_float4(mn[0], mn[1], mn[2], mn[3]);
            }
        }
    }
}

// ---- g: reduce e3 min/max partials (8 slots/batch: 4 x-blocks x 2 wm), apply BN3 ----
__global__ void k_g(const float* __restrict__ Pmax, const float* __restrict__ Pmn,
                    const float* __restrict__ a3, const float* __restrict__ s3,
                    float* __restrict__ gT) {
    int i = blockIdx.x * 256 + threadIdx.x;  // i = b*1024 + o
    if (i >= 32768) return;
    int b = i >> 10, o = i & 1023;
    float mx = -3.4e38f, mn = 3.4e38f;
#pragma unroll
    for (int t = 0; t < 8; t++) {
        mx = fmaxf(mx, Pmax[(size_t)(b * 8 + t) * 1024 + o]);
        mn = fminf(mn, Pmn[(size_t)(b * 8 + t) * 1024 + o]);
    }
    float a = a3[o];
    gT[o * 32 + b] = (a >= 0.f) ? fmaf(a, mx, s3[o]) : fmaf(a, mn, s3[o]);
}

// ---- Gh[b][o] = h_b1[o] + sum_{c<1024} h_w1[o*1088+c] * gT[c*32+b] ----
__global__ void k_gh(const float* __restrict__ hw1, const float* __restrict__ hb1,
                     const float* __restrict__ gT, float* __restrict__ Gh) {
    int o = blockIdx.x;
    int b = threadIdx.x & 31, strip = threadIdx.x >> 5;
    const float* wr = hw1 + (size_t)o * 1088 + strip * 128;
    const float* gr = gT + strip * 128 * 32 + b;
    float a0 = 0.f, a1 = 0.f;
#pragma unroll 4
    for (int c = 0; c < 128; c += 2) {
        a0 = fmaf(wr[c], gr[c * 32], a0);
        a1 = fmaf(wr[c + 1], gr[(c + 1) * 32], a1);
    }
    __shared__ float red[8][32];
    red[strip][b] = a0 + a1;
    __syncthreads();
    if (threadIdx.x < 32) {
        float acc = hb1[o];
#pragma unroll
        for (int t = 0; t < 8; t++) acc += red[t][threadIdx.x];
        Gh[threadIdx.x * 512 + o] = acc;
    }
}

// ---- h4: 128 -> 1 on [M][128] fp16; outw + per-block valid-count partials ----
__global__ void k_h4(const unsigned short* __restrict__ X, const float* __restrict__ a,
                     const float* __restrict__ s, const float* __restrict__ w4,
                     const float* __restrict__ b4, float* __restrict__ outw,
                     int* __restrict__ nvP) {
    __shared__ float la[128], ls[128], lw[128];
    int tid = threadIdx.x;
    if (tid < 128) { la[tid] = a[tid]; ls[tid] = s[tid]; lw[tid] = w4[tid]; }
    __syncthreads();
    int m = blockIdx.x * 256 + tid;
    const unsigned short* xr = X + (size_t)m * 128;
    float acc = 0.f;
#pragma unroll
    for (int c = 0; c < 128; c += 8) {
        uint4 raw = *(const uint4*)(xr + c);
        unsigned u[4] = {raw.x, raw.y, raw.z, raw.w};
#pragma unroll
        for (int t = 0; t < 4; t++) {
            float x0 = h2f((unsigned short)(u[t] & 0xffffu));
            float x1 = h2f((unsigned short)(u[t] >> 16));
            float y0 = fmaxf(fmaf(la[c + t * 2], x0, ls[c + t * 2]), 0.f);
            float y1 = fmaxf(fmaf(la[c + t * 2 + 1], x1, ls[c + t * 2 + 1]), 0.f);
            acc = fmaf(lw[c + t * 2], y0, acc);
            acc = fmaf(lw[c + t * 2 + 1], y1, acc);
        }
    }
    float wgt = 1.f + acc + b4[0];
    outw[m] = wgt;
    unsigned long long msk = __ballot(wgt > W_THRESH);
    __shared__ int cnt[4];
    int lane = tid & 63, wv = tid >> 6;
    if (lane == 0) cnt[wv] = __popcll(msk);
    __syncthreads();
    if (tid == 0) nvP[blockIdx.x] = cnt[0] + cnt[1] + cnt[2] + cnt[3];
}

// ---- per-batch weighted least squares + 3x3 Cholesky solve ----
__global__ void k_wls(const float* __restrict__ pts, const float* __restrict__ outw,
                      const int* __restrict__ nvP, float* __restrict__ beta) {
    int b = blockIdx.x;
    const float* p = pts + b * 6144;
    const float* wr = outw + b * 2048;
    int nv = 0;
#pragma unroll
    for (int i = 0; i < 8; i++) nv += nvP[b * 8 + i];
    bool use_w = nv > 3;
    float s[9] = {0, 0, 0, 0, 0, 0, 0, 0, 0};
    for (int n = threadIdx.x; n < 2048; n += 256) {
        float wgt = wr[n];
        float we = use_w ? (wgt > W_THRESH ? wgt : 0.f) : 1.f;
        float px = p[n], py = p[2048 + n], pz = p[4096 + n];
        s[0] += we * px * px; s[1] += we * px * py; s[2] += we * px;
        s[3] += we * py * py; s[4] += we * py;      s[5] += we;
        s[6] += we * px * pz; s[7] += we * py * pz; s[8] += we * pz;
    }
    for (int off = 32; off; off >>= 1)
#pragma unroll
        for (int i = 0; i < 9; i++) s[i] += __shfl_down(s[i], off);
    __shared__ float red[4][9];
    int lane = threadIdx.x & 63, wv = threadIdx.x >> 6;
    if (lane == 0)
        for (int i = 0; i < 9; i++) red[wv][i] = s[i];
    __syncthreads();
    if (threadIdx.x == 0) {
        float t[9];
        for (int i = 0; i < 9; i++) t[i] = red[0][i] + red[1][i] + red[2][i] + red[3][i];
        float a11 = t[0], a21 = t[1], a31 = t[2], a22 = t[3], a32 = t[4], a33 = t[5];
        float L11 = sqrtf(a11);
        float L21 = a21 / L11, L31 = a31 / L11;
        float L22 = sqrtf(a22 - L21 * L21);
        float L32 = (a32 - L31 * L21) / L22;
        float L33 = sqrtf(a33 - L31 * L31 - L32 * L32);
        float u1 = t[6] / L11;
        float u2 = (t[7] - L21 * u1) / L22;
        float u3 = (t[8] - L31 * u1 - L32 * u2) / L33;
        float b3 = u3 / L33;
        float b2 = (u2 - L32 * b3) / L22;
        float b1 = (u1 - L21 * b2 - L31 * b3) / L11;
        beta[b * 3 + 0] = b1;
        beta[b * 3 + 1] = b2;
        beta[b * 3 + 2] = b3;
    }
}

extern "C" void kernel_launch(void* const* d_in, const int* in_sizes, int n_in,
                              void* d_out, int out_size, void* d_ws, size_t ws_size,
                              hipStream_t stream) {
    (void)in_sizes; (void)n_in; (void)out_size; (void)ws_size;
    const float* pts   = (const float*)d_in[0];
    const float* e_w1  = (const float*)d_in[1];
    const float* e_b1  = (const float*)d_in[2];
    const float* e_g1  = (const float*)d_in[3];
    const float* e_be1 = (const float*)d_in[4];
    const float* e_w2  = (const float*)d_in[5];
    const float* e_b2  = (const float*)d_in[6];
    const float* e_g2  = (const float*)d_in[7];
    const float* e_be2 = (const float*)d_in[8];
    const float* e_w3  = (const float*)d_in[9];
    const float* e_b3  = (const float*)d_in[10];
    const float* e_g3  = (const float*)d_in[11];
    const float* e_be3 = (const float*)d_in[12];
    const float* h_w1  = (const float*)d_in[13];
    const float* h_b1  = (const float*)d_in[14];
    const float* h_g1  = (const float*)d_in[15];
    const float* h_be1 = (const float*)d_in[16];
    const float* h_w2  = (const float*)d_in[17];
    const float* h_b2  = (const float*)d_in[18];
    const float* h_g2  = (const float*)d_in[19];
    const float* h_be2 = (const float*)d_in[20];
    const float* h_w3  = (const float*)d_in[21];
    const float* h_b3  = (const float*)d_in[22];
    const float* h_g3  = (const float*)d_in[23];
    const float* h_be3 = (const float*)d_in[24];
    const float* h_w4  = (const float*)d_in[25];
    const float* h_b4  = (const float*)d_in[26];

    const size_t M = M_TOTAL;
    unsigned short* wsu = (unsigned short*)d_ws;
    unsigned short* Y1e = wsu;             // [M][64]  POST-BN
    unsigned short* Y2e = wsu + 64 * M;    // [M][128] pre-BN
    unsigned short* Y1h = wsu + 192 * M;   // [M][512] pre-BN
    unsigned short* Y2h = wsu + 704 * M;   // [M][256] pre-BN
    unsigned short* Y3h = wsu + 960 * M;   // [M][128] pre-BN
    unsigned short* We2 = wsu + 1088 * M;  // frag-ordered fp16 weights
    unsigned short* We3 = We2 + 8192;
    unsigned short* Wh1 = We3 + 131072;
    unsigned short* Wh2 = Wh1 + 32768;
    unsigned short* Wh3 = Wh2 + 131072;
    float* wsf = (float*)(Wh3 + 32768);
    float* avec = wsf;                     // 2112: e2@64 e3@192 h1@1216 h2@1728 h3@1984
    float* svec = avec + 2112;
    float* momP = svec + 2112;             // [64][9]
    float* Ps   = momP + 576;              // [<=1024 slots][<=1024]
    float* Pq   = Ps + 1024 * 1024;
    float* Pmax = Pq + 1024 * 1024;
    float* Pmn  = Pmax + 1024 * 1024;
    float* gT   = Pmn + 1024 * 1024;       // [1024][32]
    float* Gh   = gT + 32768;              // [32][512]
    int* nvP    = (int*)(Gh + 16384);      // [256]

    float* beta = (float*)d_out;           // [32][3]
    float* outw = beta + 96;               // [32][2048]

    k_wprep<<<656, 64, 0, stream>>>(e_w2, e_w3, h_w1, h_w2, h_w3, We2, We3, Wh1, Wh2, Wh3);
    k_moments<<<64, 256, 0, stream>>>(pts, momP);
    k_e1<<<256, 256, 0, stream>>>(pts, e_w1, e_b1, e_g1, e_be1, momP, Y1e);

    // e2: 64->128, K=64 ARES full-K slab (SPC=1), m-tile 256, grid 256 -> 512 slots
    k_mg<true, false, false, false, 2, 2, 2, true, 2><<<dim3(256, 1), 256, 0, stream>>>(
        We2, 128, Y1e, nullptr, nullptr, e_b2, Y2e, Ps, Pq, nullptr, nullptr);
    k_redfin<<<2, 1024, 0, stream>>>(Ps, Pq, 128, 512, e_g2, e_be2, avec + 64, svec + 64);

    // e3: 128->1024, no store, BN-in, minmax; K=128 ARES FULL-K SLAB (SB32=4, SPC=1,
    // 96KB LDS, MINW=1 -> 1 block/CU, prefetch a full chunk ahead), m-tile 512 -> 256 slots
    k_mg<false, true, false, true, 4, 4, 4, true, 1><<<dim3(128, 8), 256, 0, stream>>>(
        We3, 1024, Y2e, avec + 64, svec + 64, e_b3, nullptr, Ps, Pq, Pmax, Pmn);
    k_redfin<<<16, 1024, 0, stream>>>(Ps, Pq, 1024, 256, e_g3, e_be3, avec + 192, svec + 192);

    k_g<<<128, 256, 0, stream>>>(Pmax, Pmn, avec + 192, svec + 192, gT);
    k_gh<<<512, 256, 0, stream>>>(h_w1, h_b1, gT, Gh);

    // h1: K=64 ARES on post-BN Y1e, bias = Gh[b][o], m-tile 512 -> 256 slots
    k_mg<true, false, true, false, 2, 2, 4, true, 2><<<dim3(128, 4), 256, 0, stream>>>(
        Wh1, 512, Y1e, nullptr, nullptr, Gh, Y1h, Ps, Pq, nullptr, nullptr);
    k_redfin<<<8, 1024, 0, stream>>>(Ps, Pq, 512, 256, h_g1, h_be1, avec + 1216, svec + 1216);

    // h2: 512->256, K=512 slab-dbuf A, m-tile 256, grid (256,2) -> 512 slots
    k_mg<true, false, false, true, 16, 2, 2, false, 2><<<dim3(256, 2), 256, 0, stream>>>(
        Wh2, 256, Y1h, avec + 1216, svec + 1216, h_b2, Y2h, Ps, Pq, nullptr, nullptr);
    k_redfin<<<4, 1024, 0, stream>>>(Ps, Pq, 256, 512, h_g2, h_be2, avec + 1728, svec + 1728);

    // h3: 256->128, K=256 slab-dbuf A, m-tile 256, grid 256 -> 512 slots
    k_mg<true, false, false, true, 8, 2, 2, false, 2><<<dim3(256, 1), 256, 0, stream>>>(
        Wh3, 128, Y2h, avec + 1728, svec + 1728, h_b3, Y3h, Ps, Pq, nullptr, nullptr);
    k_redfin<<<2, 1024, 0, stream>>>(Ps, Pq, 128, 512, h_g3, h_be3, avec + 1984, svec + 1984);

    // h4 -> weights + valid-count partials, then per-batch WLS solve -> beta
    k_h4<<<256, 256, 0, stream>>>(Y3h, avec + 1984, svec + 1984, h_w4, h_b4, outw, nvP);
    k_wls<<<32, 256, 0, stream>>>(pts, outw, nvP, beta);
}

// Round 13
// 301.621 us; speedup vs baseline: 1.1073x; 1.1073x over previous
//
#include <hip/hip_runtime.h>
#include <math.h>

// SimpPointNet round 13: e3 reverted to the r11 frontier optimum (SB32=2, ARES,
// 2 blocks/CU) + CHUNKS 4->8 (grid 64x8 = 512 blocks = single residency pass at
// unchanged 8 waves/CU). r12 mapped the slab x occupancy frontier: 4blk/CU=60us,
// 2blk/CU=42us, 1blk/CU=66us -> 2 blocks/CU optimal; this keeps it while halving
// per-block fixed costs. e1-BN fusion kept (r12, ~+4us). Everything else r11/r12.
// M = B*N = 65536, m = b*2048 + n.

#define M_TOTAL 65536
#define BN_EPS 1e-5f
#define W_THRESH 1e-4f

typedef __attribute__((ext_vector_type(8))) _Float16 f16x8;
typedef __attribute__((ext_vector_type(2))) _Float16 half2v;
typedef __attribute__((ext_vector_type(4))) float f32x4;

__device__ __forceinline__ unsigned short f2h(float f) {
    _Float16 h = (_Float16)f;
    return __builtin_bit_cast(unsigned short, h);
}
__device__ __forceinline__ float h2f(unsigned short u) {
    return (float)__builtin_bit_cast(_Float16, u);
}

// async global->LDS, 16B per lane; per-lane source vaddr, LDS dest = uniform base + lane*16
__device__ __forceinline__ void cp16(unsigned short* lds, const unsigned short* g) {
    __builtin_amdgcn_global_load_lds(
        (const __attribute__((address_space(1))) unsigned int*)(const void*)g,
        (__attribute__((address_space(3))) unsigned int*)(void*)lds,
        16, 0, 0);
}

// ---- convert all 5 GEMM weight matrices to MFMA-fragment-ordered fp16 ----
// Tile (ob, kb32, ot): 64 lanes x 8 halves; lane l -> W[ob*128+ot*16+(l&15)][kb32*32+(l>>4)*8..+8]
// Flat: Wf[ ((ob*KB32 + kb32)*8 + ot)*512 + l*8 ]
__global__ void k_wprep(const float* __restrict__ e_w2, const float* __restrict__ e_w3,
                        const float* __restrict__ hw1, const float* __restrict__ h_w2,
                        const float* __restrict__ h_w3,
                        unsigned short* We2, unsigned short* We3, unsigned short* Wh1,
                        unsigned short* Wh2, unsigned short* Wh3) {
    int t = blockIdx.x;
    const float* W; int ldw, KB; unsigned short* D; int rel;
    if (t < 16)       { W = e_w2;       ldw = 64;   KB = 2;  D = We2; rel = t; }
    else if (t < 272) { W = e_w3;       ldw = 128;  KB = 4;  D = We3; rel = t - 16; }
    else if (t < 336) { W = hw1 + 1024; ldw = 1088; KB = 2;  D = Wh1; rel = t - 272; }
    else if (t < 592) { W = h_w2;       ldw = 512;  KB = 16; D = Wh2; rel = t - 336; }
    else              { W = h_w3;       ldw = 256;  KB = 8;  D = Wh3; rel = t - 592; }
    int ot = rel & 7, kb = (rel >> 3) % KB, ob = rel / (8 * KB);
    int l = threadIdx.x;
    int o = ob * 128 + ot * 16 + (l & 15);
    int k = kb * 32 + (l >> 4) * 8;
    const float* src = W + (size_t)o * ldw + k;
    float4 wa = *(const float4*)src;
    float4 wb = *(const float4*)(src + 4);
    uint4 pk;
    pk.x = (unsigned)f2h(wa.x) | ((unsigned)f2h(wa.y) << 16);
    pk.y = (unsigned)f2h(wa.z) | ((unsigned)f2h(wa.w) << 16);
    pk.z = (unsigned)f2h(wb.x) | ((unsigned)f2h(wb.y) << 16);
    pk.w = (unsigned)f2h(wb.z) | ((unsigned)f2h(wb.w) << 16);
    *(uint4*)(D + (size_t)rel * 512 + l * 8) = pk;
}

// ---- point second moments -> per-block partials momP[64][9] ----
__global__ void k_moments(const float* __restrict__ pts, float* __restrict__ momP) {
    float s[9] = {0,0,0,0,0,0,0,0,0};
    for (int m = blockIdx.x * 256 + threadIdx.x; m < M_TOTAL; m += gridDim.x * 256) {
        int b = m >> 11, n = m & 2047;
        const float* p = pts + b * 6144 + n;
        float x = p[0], y = p[2048], z = p[4096];
        s[0] += x; s[1] += y; s[2] += z;
        s[3] += x * x; s[4] += y * y; s[5] += z * z;
        s[6] += x * y; s[7] += x * z; s[8] += y * z;
    }
    for (int off = 32; off; off >>= 1)
#pragma unroll
        for (int i = 0; i < 9; i++) s[i] += __shfl_down(s[i], off);
    __shared__ float red[4][9];
    int lane = threadIdx.x & 63, wv = threadIdx.x >> 6;
    if (lane == 0)
        for (int i = 0; i < 9; i++) red[wv][i] = s[i];
    __syncthreads();
    if (threadIdx.x < 9)
        momP[blockIdx.x * 9 + threadIdx.x] =
            red[0][threadIdx.x] + red[1][threadIdx.x] + red[2][threadIdx.x] + red[3][threadIdx.x];
}

// ---- e1: 3 -> 64, POST-BN+ReLU fp16 output [M][64]; BN params computed in-block ----
__global__ void k_e1(const float* __restrict__ pts, const float* __restrict__ w,
                     const float* __restrict__ bias, const float* __restrict__ g1,
                     const float* __restrict__ be1, const float* __restrict__ momP,
                     unsigned short* __restrict__ Y) {
    __shared__ float wl[192], bl[64], al[64], sl[64], m9[9];
    int tid = threadIdx.x;
    if (tid < 192) wl[tid] = w[tid];
    if (tid < 64) bl[tid] = bias[tid];
    if (tid >= 192 && tid < 201) {
        int i = tid - 192;
        float t = 0.f;
        for (int k = 0; k < 64; k++) t += momP[k * 9 + i];
        m9[i] = t;
    }
    __syncthreads();
    if (tid < 64) {
        int o = tid;
        float w0 = wl[o * 3], w1 = wl[o * 3 + 1], w2 = wl[o * 3 + 2], b = bl[o];
        float wS1 = w0 * m9[0] + w1 * m9[1] + w2 * m9[2];
        float sum = wS1 + 65536.f * b;
        float sumsq = w0 * w0 * m9[3] + w1 * w1 * m9[4] + w2 * w2 * m9[5]
                    + 2.f * (w0 * w1 * m9[6] + w0 * w2 * m9[7] + w1 * w2 * m9[8])
                    + 2.f * b * wS1 + 65536.f * b * b;
        float mean = sum * (1.f / 65536.f);
        float var = sumsq * (1.f / 65536.f) - mean * mean;
        float ac = g1[o] * rsqrtf(var + BN_EPS);
        al[o] = ac;
        sl[o] = be1[o] - mean * ac;
    }
    __syncthreads();
    int m = blockIdx.x * 256 + tid;
    int b = m >> 11, n = m & 2047;
    const float* p = pts + b * 6144 + n;
    float px = p[0], py = p[2048], pz = p[4096];
    unsigned short* yr = Y + (size_t)m * 64;
#pragma unroll
    for (int o8 = 0; o8 < 64; o8 += 8) {
        unsigned pkw[4];
#pragma unroll
        for (int t = 0; t < 4; t++) {
            int o = o8 + t * 2;
            float v0 = fmaf(wl[o * 3 + 0], px, fmaf(wl[o * 3 + 1], py, fmaf(wl[o * 3 + 2], pz, bl[o])));
            float v1 = fmaf(wl[o * 3 + 3], px, fmaf(wl[o * 3 + 4], py, fmaf(wl[o * 3 + 5], pz, bl[o + 1])));
            float y0 = fmaxf(fmaf(al[o], v0, sl[o]), 0.f);
            float y1 = fmaxf(fmaf(al[o + 1], v1, sl[o + 1]), 0.f);
            pkw[t] = (unsigned)f2h(y0) | ((unsigned)f2h(y1) << 16);
        }
        uint4 pk; pk.x = pkw[0]; pk.y = pkw[1]; pk.z = pkw[2]; pk.w = pkw[3];
        *(uint4*)(yr + o8) = pk;
    }
}

// ---- reduce S slot partials -> BN (a,s) ----
__global__ void k_redfin(const float* __restrict__ Ps, const float* __restrict__ Pq,
                         int C, int S,
                         const float* __restrict__ g, const float* __restrict__ be,
                         float* __restrict__ a, float* __restrict__ s) {
    int cl = threadIdx.x & 63, strip = threadIdx.x >> 6;  // 16 strips x 64 ch
    int c = blockIdx.x * 64 + cl;
    float sm = 0.f, q = 0.f;
    for (int k = strip; k < S; k += 16) {
        sm += Ps[(size_t)k * C + c];
        q += Pq[(size_t)k * C + c];
    }
    __shared__ float rs[16][64], rq[16][64];
    rs[strip][cl] = sm; rq[strip][cl] = q;
    __syncthreads();
    if (threadIdx.x < 64) {
        float S2 = 0.f, Q = 0.f;
#pragma unroll
        for (int t = 0; t < 16; t++) { S2 += rs[t][cl]; Q += rq[t][cl]; }
        float mean = S2 * (1.f / M_TOTAL);
        float var = Q * (1.f / M_TOTAL) - mean * mean;
        float ac = g[c] * rsqrtf(var + BN_EPS);
        a[c] = ac;
        s[c] = be[c] - mean * ac;
    }
}

// ---- unified slab-pipelined MFMA GEMM (r11 structure) ----
template <bool STORE, bool MINMAX, bool BIAS_BO, bool BNB, int KB32, int SB32, int CHUNKS, bool ARES, int MINW>
__launch_bounds__(256, MINW)
__global__ void k_mg(const unsigned short* __restrict__ Wf, int O,
                     const unsigned short* __restrict__ X,
                     const float* __restrict__ a_in, const float* __restrict__ s_in,
                     const float* __restrict__ bias,
                     unsigned short* __restrict__ Y,
                     float* __restrict__ Psum, float* __restrict__ Psq,
                     float* __restrict__ Pmax, float* __restrict__ Pmn) {
    constexpr int K = KB32 * 32;
    constexpr int SPC = KB32 / SB32;      // steps per chunk
    constexpr int NSTEPS = CHUNKS * SPC;
    constexpr int BT = SB32 * 8;          // tiles per slab
    constexpr int BSZ = BT * 512;         // halves per buffer
    constexpr int ASZ = ARES ? KB32 * 8 * 512 : 2 * BSZ;
    __shared__ __align__(16) unsigned short sA[ASZ];
    __shared__ __align__(16) unsigned short sB[2][BSZ];
    __shared__ _Float16 sah[BNB ? K : 2], ssb[BNB ? K : 2];
    int tid = threadIdx.x, lane = tid & 63, wave = tid >> 6;
    int wo = wave >> 1, wm = wave & 1;
    int q = lane >> 4, lc = lane & 15;
    int m0 = blockIdx.x * (128 * CHUNKS), o0 = blockIdx.y * 128;
    int bidx = m0 >> 11;

    if constexpr (BNB)
        for (int c = tid; c < K; c += 256) {
            sah[c] = (_Float16)a_in[c];
            ssb[c] = (_Float16)s_in[c];
        }

    const unsigned short* aSrc = Wf + (size_t)blockIdx.y * KB32 * 8 * 512 + lane * 8;

    auto stageB = [&](int cc, int ssl, int buf) {
#pragma unroll
        for (int t = wave; t < BT; t += 4) {
            int kb = t >> 3, mt = t & 7;
            const unsigned short* src = X
                + (size_t)(m0 + cc * 128 + mt * 16 + (lane & 15)) * K
                + (ssl * SB32 + kb) * 32 + ((lane >> 4) * 8);
            cp16(&sB[buf][t * 512], src);
        }
    };
    auto stageA = [&](int ssl, int buf) {
#pragma unroll
        for (int t = wave; t < BT; t += 4)
            cp16(&sA[buf * BSZ + t * 512], aSrc + (size_t)(ssl * SB32 * 8 + t) * 512);
    };

    // initial staging
    if constexpr (ARES) {
#pragma unroll
        for (int t = wave; t < KB32 * 8; t += 4)
            cp16(&sA[t * 512], aSrc + (size_t)t * 512);
    } else {
        stageA(0, 0);
    }
    stageB(0, 0, 0);

    f32x4 acc[4][4];
#pragma unroll
    for (int i = 0; i < 4; i++)
#pragma unroll
        for (int j = 0; j < 4; j++) acc[i][j] = (f32x4){0.f, 0.f, 0.f, 0.f};
    float sAcc[4][4] = {}, qAcc[4][4] = {};
    float mxA[4][4], mnA[4][4];
    if constexpr (MINMAX) {
#pragma unroll
        for (int i = 0; i < 4; i++)
#pragma unroll
            for (int r = 0; r < 4; r++) { mxA[i][r] = -3.4e38f; mnA[i][r] = 3.4e38f; }
    }

    __syncthreads();  // startup drain: A(+slab0) and B slab 0 landed

    for (int c = 0; c < CHUNKS; c++) {
#pragma unroll
        for (int ss = 0; ss < SPC; ss++) {
            if (c > 0 || ss > 0) __syncthreads();  // drains staging issued one step ago
            int step = c * SPC + ss;
            if (step + 1 < NSTEPS) {               // prefetch next step
                int wrap = (ss == SPC - 1) ? 1 : 0;
                int nc = c + wrap;
                int nss = wrap ? 0 : ss + 1;
                int nbuf = (step + 1) & 1;
                stageB(nc, nss, nbuf);
                if constexpr (!ARES) stageA(nss, nbuf);
            }
            int p = step & 1;
            const unsigned short* bb = sB[p];
            const unsigned short* ab = ARES ? sA : sA + p * BSZ;
#pragma unroll
            for (int kb = 0; kb < SB32; kb++) {
                f16x8 af[4], bf[4];
                int tA = ARES ? ((ss * SB32 + kb) * 8) : (kb * 8);
#pragma unroll
                for (int i = 0; i < 4; i++)
                    af[i] = *(const f16x8*)&ab[(tA + wo * 4 + i) * 512 + lane * 8];
#pragma unroll
                for (int j = 0; j < 4; j++)
                    bf[j] = *(const f16x8*)&bb[(kb * 8 + wm * 4 + j) * 512 + lane * 8];

                if constexpr (BNB) {
                    int ka = (ss * SB32 + kb) * 32 + (lane >> 4) * 8;
                    half2v a2[4], s2[4];
#pragma unroll
                    for (int t = 0; t < 4; t++) {
                        a2[t] = *(const half2v*)&sah[ka + 2 * t];
                        s2[t] = *(const half2v*)&ssb[ka + 2 * t];
                    }
                    half2v z2 = (half2v)(_Float16)0;
#pragma unroll
                    for (int j = 0; j < 4; j++) {
                        half2v* pb = (half2v*)&bf[j];
#pragma unroll
                        for (int t = 0; t < 4; t++)
                            pb[t] = __builtin_elementwise_max(a2[t] * pb[t] + s2[t], z2);
                    }
                }
#pragma unroll
                for (int i = 0; i < 4; i++)
#pragma unroll
                    for (int j = 0; j < 4; j++)
                        acc[i][j] = __builtin_amdgcn_mfma_f32_16x16x32_f16(af[i], bf[j], acc[i][j], 0, 0, 0);
            }
        }

        // ---- chunk epilogue: fold stats; store via transpose in retired B buffer ----
#pragma unroll
        for (int i = 0; i < 4; i++)
#pragma unroll
            for (int j = 0; j < 4; j++)
#pragma unroll
                for (int r = 0; r < 4; r++) {
                    float v = acc[i][j][r];
                    sAcc[i][r] += v;
                    qAcc[i][r] = fmaf(v, v, qAcc[i][r]);
                    if constexpr (MINMAX) {
                        mxA[i][r] = fmaxf(mxA[i][r], v);
                        mnA[i][r] = fminf(mnA[i][r], v);
                    }
                }

        if constexpr (STORE) {
            int pLast = (c * SPC + SPC - 1) & 1;
            short* sT = (short*)&sB[pLast][0];  // retired buffer; prefetch targets the other
            int mbase = m0 + c * 128;
            __syncthreads();  // all waves done reading sB[pLast]
#pragma unroll
            for (int ch = 0; ch < 4; ch++) {
                if (wm == (ch >> 1)) {
                    int jlo = (ch & 1) * 2;
#pragma unroll
                    for (int i = 0; i < 4; i++) {
                        int ob = o0 + wo * 64 + i * 16 + q * 4;
                        float b0 = BIAS_BO ? bias[bidx * O + ob + 0] : bias[ob + 0];
                        float b1 = BIAS_BO ? bias[bidx * O + ob + 1] : bias[ob + 1];
                        float b2 = BIAS_BO ? bias[bidx * O + ob + 2] : bias[ob + 2];
                        float b3 = BIAS_BO ? bias[bidx * O + ob + 3] : bias[ob + 3];
#pragma unroll
                        for (int jj = 0; jj < 2; jj++) {
                            int j = jlo + jj;
                            int row = jj * 16 + lc;
                            int c0 = wo * 64 + i * 16 + q * 4;
                            uint2 pk;
                            pk.x = (unsigned)f2h(acc[i][j][0] + b0) | ((unsigned)f2h(acc[i][j][1] + b1) << 16);
                            pk.y = (unsigned)f2h(acc[i][j][2] + b2) | ((unsigned)f2h(acc[i][j][3] + b3) << 16);
                            *(uint2*)&sT[row * 136 + c0] = pk;
                        }
                    }
                }
                __syncthreads();
                {
                    int row = tid >> 4, c0 = (tid & 15) * 8;
#pragma unroll
                    for (int rr = 0; rr < 2; rr++) {
                        int r2 = row + rr * 16;
                        int m = mbase + ch * 32 + r2;
                        uint4 v = *(const uint4*)&sT[r2 * 136 + c0];
                        *(uint4*)(Y + (size_t)m * O + o0 + c0) = v;
                    }
                }
                __syncthreads();
            }
        }

        if (c + 1 < CHUNKS) {
#pragma unroll
            for (int i = 0; i < 4; i++)
#pragma unroll
                for (int j = 0; j < 4; j++) acc[i][j] = (f32x4){0.f, 0.f, 0.f, 0.f};
        }
    }

    // ---- final: 16-lane reduce, bias correction, one partial write per block ----
    int slot = blockIdx.x * 2 + wm;
    const float NM = 64.f * CHUNKS;
#pragma unroll
    for (int i = 0; i < 4; i++) {
        int ob = o0 + wo * 64 + i * 16 + q * 4;
        float s4[4], q4[4], mx[4], mn[4];
#pragma unroll
        for (int r = 0; r < 4; r++) {
            s4[r] = sAcc[i][r]; q4[r] = qAcc[i][r];
            if constexpr (MINMAX) { mx[r] = mxA[i][r]; mn[r] = mnA[i][r]; }
        }
#pragma unroll
        for (int off = 1; off < 16; off <<= 1)
#pragma unroll
            for (int r = 0; r < 4; r++) {
                s4[r] += __shfl_xor(s4[r], off);
                q4[r] += __shfl_xor(q4[r], off);
                if constexpr (MINMAX) {
                    mx[r] = fmaxf(mx[r], __shfl_xor(mx[r], off));
                    mn[r] = fminf(mn[r], __shfl_xor(mn[r], off));
                }
            }
        if (lc == 0) {
            float S4[4], Q4[4];
#pragma unroll
            for (int r = 0; r < 4; r++) {
                float bv = BIAS_BO ? bias[bidx * O + ob + r] : bias[ob + r];
                S4[r] = s4[r] + NM * bv;
                Q4[r] = q4[r] + 2.f * bv * s4[r] + NM * bv * bv;
                if constexpr (MINMAX) { mx[r] += bv; mn[r] += bv; }
            }
            *(float4*)&Psum[(size_t)slot * O + ob] = make_float4(S4[0], S4[1], S4[2], S4[3]);
            *(float4*)&Psq[(size_t)slot * O + ob] = make_float4(Q4[0], Q4[1], Q4[2], Q4[3]);
            if constexpr (MINMAX) {
                *(float4*)&Pmax[(size_t)slot * O + ob] = make_float4(mx[0], mx[1], mx[2], mx[3]);
                *(float4*)&Pmn[(size_t)slot * O + ob] = make_float4(mn[0], mn[1], mn[2], mn[3]);
            }
        }
    }
}

// ---- g: reduce e3 min/max partials (4 slots/batch: 2 m-blocks x 2 wm), apply BN3 ----
__global__ void k_g(const float* __restrict__ Pmax, const float* __restrict__ Pmn,
                    const float* __restrict__ a3, const float* __restrict__ s3,
                    float* __restrict__ gT) {
    int i = blockIdx.x * 256 + threadIdx.x;  // i = b*1024 + o
    if (i >= 32768) return;
    int b = i >> 10, o = i & 1023;
    float mx = -3.4e38f, mn = 3.4e38f;
#pragma unroll
    for (int t = 0; t < 4; t++) {
        mx = fmaxf(mx, Pmax[(size_t)(b * 4 + t) * 1024 + o]);
        mn = fminf(mn, Pmn[(size_t)(b * 4 + t) * 1024 + o]);
    }
    float a = a3[o];
    gT[o * 32 + b] = (a >= 0.f) ? fmaf(a, mx, s3[o]) : fmaf(a, mn, s3[o]);
}

// ---- Gh[b][o] = h_b1[o] + sum_{c<1024} h_w1[o*1088+c] * gT[c*32+b] ----
__global__ void k_gh(const float* __restrict__ hw1, const float* __restrict__ hb1,
                     const float* __restrict__ gT, float* __restrict__ Gh) {
    int o = blockIdx.x;
    int b = threadIdx.x & 31, strip = threadIdx.x >> 5;
    const float* wr = hw1 + (size_t)o * 1088 + strip * 128;
    const float* gr = gT + strip * 128 * 32 + b;
    float a0 = 0.f, a1 = 0.f;
#pragma unroll 4
    for (int c = 0; c < 128; c += 2) {
        a0 = fmaf(wr[c], gr[c * 32], a0);
        a1 = fmaf(wr[c + 1], gr[(c + 1) * 32], a1);
    }
    __shared__ float red[8][32];
    red[strip][b] = a0 + a1;
    __syncthreads();
    if (threadIdx.x < 32) {
        float acc = hb1[o];
#pragma unroll
        for (int t = 0; t < 8; t++) acc += red[t][threadIdx.x];
        Gh[threadIdx.x * 512 + o] = acc;
    }
}

// ---- h4: 128 -> 1 on [M][128] fp16; outw + per-block valid-count partials ----
__global__ void k_h4(const unsigned short* __restrict__ X, const float* __restrict__ a,
                     const float* __restrict__ s, const float* __restrict__ w4,
                     const float* __restrict__ b4, float* __restrict__ outw,
                     int* __restrict__ nvP) {
    __shared__ float la[128], ls[128], lw[128];
    int tid = threadIdx.x;
    if (tid < 128) { la[tid] = a[tid]; ls[tid] = s[tid]; lw[tid] = w4[tid]; }
    __syncthreads();
    int m = blockIdx.x * 256 + tid;
    const unsigned short* xr = X + (size_t)m * 128;
    float acc = 0.f;
#pragma unroll
    for (int c = 0; c < 128; c += 8) {
        uint4 raw = *(const uint4*)(xr + c);
        unsigned u[4] = {raw.x, raw.y, raw.z, raw.w};
#pragma unroll
        for (int t = 0; t < 4; t++) {
            float x0 = h2f((unsigned short)(u[t] & 0xffffu));
            float x1 = h2f((unsigned short)(u[t] >> 16));
            float y0 = fmaxf(fmaf(la[c + t * 2], x0, ls[c + t * 2]), 0.f);
            float y1 = fmaxf(fmaf(la[c + t * 2 + 1], x1, ls[c + t * 2 + 1]), 0.f);
            acc = fmaf(lw[c + t * 2], y0, acc);
            acc = fmaf(lw[c + t * 2 + 1], y1, acc);
        }
    }
    float wgt = 1.f + acc + b4[0];
    outw[m] = wgt;
    unsigned long long msk = __ballot(wgt > W_THRESH);
    __shared__ int cnt[4];
    int lane = tid & 63, wv = tid >> 6;
    if (lane == 0) cnt[wv] = __popcll(msk);
    __syncthreads();
    if (tid == 0) nvP[blockIdx.x] = cnt[0] + cnt[1] + cnt[2] + cnt[3];
}

// ---- per-batch weighted least squares + 3x3 Cholesky solve ----
__global__ void k_wls(const float* __restrict__ pts, const float* __restrict__ outw,
                      const int* __restrict__ nvP, float* __restrict__ beta) {
    int b = blockIdx.x;
    const float* p = pts + b * 6144;
    const float* wr = outw + b * 2048;
    int nv = 0;
#pragma unroll
    for (int i = 0; i < 8; i++) nv += nvP[b * 8 + i];
    bool use_w = nv > 3;
    float s[9] = {0, 0, 0, 0, 0, 0, 0, 0, 0};
    for (int n = threadIdx.x; n < 2048; n += 256) {
        float wgt = wr[n];
        float we = use_w ? (wgt > W_THRESH ? wgt : 0.f) : 1.f;
        float px = p[n], py = p[2048 + n], pz = p[4096 + n];
        s[0] += we * px * px; s[1] += we * px * py; s[2] += we * px;
        s[3] += we * py * py; s[4] += we * py;      s[5] += we;
        s[6] += we * px * pz; s[7] += we * py * pz; s[8] += we * pz;
    }
    for (int off = 32; off; off >>= 1)
#pragma unroll
        for (int i = 0; i < 9; i++) s[i] += __shfl_down(s[i], off);
    __shared__ float red[4][9];
    int lane = threadIdx.x & 63, wv = threadIdx.x >> 6;
    if (lane == 0)
        for (int i = 0; i < 9; i++) red[wv][i] = s[i];
    __syncthreads();
    if (threadIdx.x == 0) {
        float t[9];
        for (int i = 0; i < 9; i++) t[i] = red[0][i] + red[1][i] + red[2][i] + red[3][i];
        float a11 = t[0], a21 = t[1], a31 = t[2], a22 = t[3], a32 = t[4], a33 = t[5];
        float L11 = sqrtf(a11);
        float L21 = a21 / L11, L31 = a31 / L11;
        float L22 = sqrtf(a22 - L21 * L21);
        float L32 = (a32 - L31 * L21) / L22;
        float L33 = sqrtf(a33 - L31 * L31 - L32 * L32);
        float u1 = t[6] / L11;
        float u2 = (t[7] - L21 * u1) / L22;
        float u3 = (t[8] - L31 * u1 - L32 * u2) / L33;
        float b3 = u3 / L33;
        float b2 = (u2 - L32 * b3) / L22;
        float b1 = (u1 - L21 * b2 - L31 * b3) / L11;
        beta[b * 3 + 0] = b1;
        beta[b * 3 + 1] = b2;
        beta[b * 3 + 2] = b3;
    }
}

extern "C" void kernel_launch(void* const* d_in, const int* in_sizes, int n_in,
                              void* d_out, int out_size, void* d_ws, size_t ws_size,
                              hipStream_t stream) {
    (void)in_sizes; (void)n_in; (void)out_size; (void)ws_size;
    const float* pts   = (const float*)d_in[0];
    const float* e_w1  = (const float*)d_in[1];
    const float* e_b1  = (const float*)d_in[2];
    const float* e_g1  = (const float*)d_in[3];
    const float* e_be1 = (const float*)d_in[4];
    const float* e_w2  = (const float*)d_in[5];
    const float* e_b2  = (const float*)d_in[6];
    const float* e_g2  = (const float*)d_in[7];
    const float* e_be2 = (const float*)d_in[8];
    const float* e_w3  = (const float*)d_in[9];
    const float* e_b3  = (const float*)d_in[10];
    const float* e_g3  = (const float*)d_in[11];
    const float* e_be3 = (const float*)d_in[12];
    const float* h_w1  = (const float*)d_in[13];
    const float* h_b1  = (const float*)d_in[14];
    const float* h_g1  = (const float*)d_in[15];
    const float* h_be1 = (const float*)d_in[16];
    const float* h_w2  = (const float*)d_in[17];
    const float* h_b2  = (const float*)d_in[18];
    const float* h_g2  = (const float*)d_in[19];
    const float* h_be2 = (const float*)d_in[20];
    const float* h_w3  = (const float*)d_in[21];
    const float* h_b3  = (const float*)d_in[22];
    const float* h_g3  = (const float*)d_in[23];
    const float* h_be3 = (const float*)d_in[24];
    const float* h_w4  = (const float*)d_in[25];
    const float* h_b4  = (const float*)d_in[26];

    const size_t M = M_TOTAL;
    unsigned short* wsu = (unsigned short*)d_ws;
    unsigned short* Y1e = wsu;             // [M][64]  POST-BN
    unsigned short* Y2e = wsu + 64 * M;    // [M][128] pre-BN
    unsigned short* Y1h = wsu + 192 * M;   // [M][512] pre-BN
    unsigned short* Y2h = wsu + 704 * M;   // [M][256] pre-BN
    unsigned short* Y3h = wsu + 960 * M;   // [M][128] pre-BN
    unsigned short* We2 = wsu + 1088 * M;  // frag-ordered fp16 weights
    unsigned short* We3 = We2 + 8192;
    unsigned short* Wh1 = We3 + 131072;
    unsigned short* Wh2 = Wh1 + 32768;
    unsigned short* Wh3 = Wh2 + 131072;
    float* wsf = (float*)(Wh3 + 32768);
    float* avec = wsf;                     // 2112: e2@64 e3@192 h1@1216 h2@1728 h3@1984
    float* svec = avec + 2112;
    float* momP = svec + 2112;             // [64][9]
    float* Ps   = momP + 576;              // [<=1024 slots][<=1024]
    float* Pq   = Ps + 1024 * 1024;
    float* Pmax = Pq + 1024 * 1024;
    float* Pmn  = Pmax + 1024 * 1024;
    float* gT   = Pmn + 1024 * 1024;       // [1024][32]
    float* Gh   = gT + 32768;              // [32][512]
    int* nvP    = (int*)(Gh + 16384);      // [256]

    float* beta = (float*)d_out;           // [32][3]
    float* outw = beta + 96;               // [32][2048]

    k_wprep<<<656, 64, 0, stream>>>(e_w2, e_w3, h_w1, h_w2, h_w3, We2, We3, Wh1, Wh2, Wh3);
    k_moments<<<64, 256, 0, stream>>>(pts, momP);
    k_e1<<<256, 256, 0, stream>>>(pts, e_w1, e_b1, e_g1, e_be1, momP, Y1e);

    // e2: 64->128, K=64 ARES, m-tile 256, grid 256 -> 512 slots
    k_mg<true, false, false, false, 2, 2, 2, true, 2><<<dim3(256, 1), 256, 0, stream>>>(
        We2, 128, Y1e, nullptr, nullptr, e_b2, Y2e, Ps, Pq, nullptr, nullptr);
    k_redfin<<<2, 1024, 0, stream>>>(Ps, Pq, 128, 512, e_g2, e_be2, avec + 64, svec + 64);

    // e3: 128->1024, no store, BN-in, minmax; K=128 ARES, SB32=2 (r11 frontier optimum,
    // 66KB LDS -> 2 blocks/CU), CHUNKS=8 -> grid (64,8) = 512 blocks = ONE residency pass
    k_mg<false, true, false, true, 4, 2, 8, true, 2><<<dim3(64, 8), 256, 0, stream>>>(
        We3, 1024, Y2e, avec + 64, svec + 64, e_b3, nullptr, Ps, Pq, Pmax, Pmn);
    k_redfin<<<16, 1024, 0, stream>>>(Ps, Pq, 1024, 128, e_g3, e_be3, avec + 192, svec + 192);

    k_g<<<128, 256, 0, stream>>>(Pmax, Pmn, avec + 192, svec + 192, gT);
    k_gh<<<512, 256, 0, stream>>>(h_w1, h_b1, gT, Gh);

    // h1: K=64 ARES on post-BN Y1e, bias = Gh[b][o], m-tile 512 -> 256 slots
    k_mg<true, false, true, false, 2, 2, 4, true, 2><<<dim3(128, 4), 256, 0, stream>>>(
        Wh1, 512, Y1e, nullptr, nullptr, Gh, Y1h, Ps, Pq, nullptr, nullptr);
    k_redfin<<<8, 1024, 0, stream>>>(Ps, Pq, 512, 256, h_g1, h_be1, avec + 1216, svec + 1216);

    // h2: 512->256, K=512 slab-dbuf A, m-tile 256, grid (256,2) -> 512 slots
    k_mg<true, false, false, true, 16, 2, 2, false, 2><<<dim3(256, 2), 256, 0, stream>>>(
        Wh2, 256, Y1h, avec + 1216, svec + 1216, h_b2, Y2h, Ps, Pq, nullptr, nullptr);
    k_redfin<<<4, 1024, 0, stream>>>(Ps, Pq, 256, 512, h_g2, h_be2, avec + 1728, svec + 1728);

    // h3: 256->128, K=256 slab-dbuf A, m-tile 256, grid 256 -> 512 slots
    k_mg<true, false, false, true, 8, 2, 2, false, 2><<<dim3(256, 1), 256, 0, stream>>>(
        Wh3, 128, Y2h, avec + 1728, svec + 1728, h_b3, Y3h, Ps, Pq, nullptr, nullptr);
    k_redfin<<<2, 1024, 0, stream>>>(Ps, Pq, 128, 512, h_g3, h_be3, avec + 1984, svec + 1984);

    // h4 -> weights + valid-count partials, then per-batch WLS solve -> beta
    k_h4<<<256, 256, 0, stream>>>(Y3h, avec + 1984, svec + 1984, h_w4, h_b4, outw, nvP);
    k_wls<<<32, 256, 0, stream>>>(pts, outw, nvP, beta);
}